// Round 5
// baseline (252.631 us; speedup 1.0000x reference)
//
#include <hip/hip_runtime.h>

// ---------- types ----------
typedef unsigned short u16;
typedef __attribute__((ext_vector_type(4))) float f32x4;
typedef __attribute__((ext_vector_type(8))) short s16x8;
typedef __attribute__((ext_vector_type(8))) __bf16 bf16x8;
typedef __attribute__((ext_vector_type(4))) unsigned short u16x4;

#define LOG2E 1.44269504088896340736f

__device__ __forceinline__ u16 f2bf(float f) {
  unsigned u = __builtin_bit_cast(unsigned, f);
  u += 0x7fffu + ((u >> 16) & 1u);  // RNE
  return (u16)(u >> 16);
}

__device__ __forceinline__ f32x4 mfma16(s16x8 a, s16x8 b, f32x4 c) {
  return __builtin_amdgcn_mfma_f32_16x16x32_bf16(
      __builtin_bit_cast(bf16x8, a), __builtin_bit_cast(bf16x8, b), c, 0, 0, 0);
}

// XOR-swizzle mask for u16-indexed rows of 64 elems (128B): flips idx bits 3..5.
__device__ __forceinline__ int swzm(int row) {
  return (((row & 7) ^ ((row >> 3) & 7)) << 3);
}

// global -> LDS direct copy, 16B per lane. LDS dest must be uniform-base + lane*16.
#define GLOAD_LDS16(g, l)                                                      \
  __builtin_amdgcn_global_load_lds(                                            \
      (const __attribute__((address_space(1))) unsigned int*)(g),              \
      (__attribute__((address_space(3))) unsigned int*)(l), 16, 0, 0)

// ---------- cast x f32 -> bf16 (4 elems/thread, exact grid) ----------
__global__ __launch_bounds__(256) void k_cast_bf16(const float* __restrict__ in,
                                                   u16* __restrict__ out) {
  int i = (blockIdx.x * 256 + threadIdx.x) * 4;
  float4 v = *(const float4*)(in + i);
  u16x4 o = {f2bf(v.x), f2bf(v.y), f2bf(v.z), f2bf(v.w)};
  *(u16x4*)(out + i) = o;
}

// ---------- Wq/Wk/Wv [H,C,D] f32 -> Wt [3*H*D][C] bf16 (B^T layout) ----------
__global__ __launch_bounds__(256) void k_wqkv(const float* __restrict__ Wq,
                                              const float* __restrict__ Wk,
                                              const float* __restrict__ Wv,
                                              u16* __restrict__ Wt) {
  int z = blockIdx.y;  // 0..47
  int qkv = z >> 4, h = z & 15;
  const float* in = (qkv == 0 ? Wq : (qkv == 1 ? Wk : Wv)) + h * 1024 * 64;
  int c0 = blockIdx.x * 64;
  __shared__ float tile[64][65];
  int t = threadIdx.x;
  int rA = t >> 4, cA = (t & 15) * 4;
#pragma unroll
  for (int rr = 0; rr < 4; ++rr) {
    int c = rr * 16 + rA;
    float4 v = *(const float4*)(in + (c0 + c) * 64 + cA);
    tile[c][cA] = v.x; tile[c][cA + 1] = v.y; tile[c][cA + 2] = v.z; tile[c][cA + 3] = v.w;
  }
  __syncthreads();
  int obase = qkv * 1024 + h * 64;
#pragma unroll
  for (int rr = 0; rr < 4; ++rr) {
    int d = rr * 16 + rA;
    u16x4 o = {f2bf(tile[cA][d]), f2bf(tile[cA + 1][d]), f2bf(tile[cA + 2][d]),
               f2bf(tile[cA + 3][d])};
    *(u16x4*)(Wt + (obase + d) * 1024 + c0 + cA) = o;
  }
}

// ---------- Wp [1024][1024] f32 -> WpT [n][k] bf16 ----------
__global__ __launch_bounds__(256) void k_wp(const float* __restrict__ in,
                                            u16* __restrict__ out) {
  int r0 = blockIdx.y * 64, c0 = blockIdx.x * 64;
  __shared__ float tile[64][65];
  int t = threadIdx.x;
  int rA = t >> 4, cA = (t & 15) * 4;
#pragma unroll
  for (int rr = 0; rr < 4; ++rr) {
    int r = rr * 16 + rA;
    float4 v = *(const float4*)(in + (r0 + r) * 1024 + c0 + cA);
    tile[r][cA] = v.x; tile[r][cA + 1] = v.y; tile[r][cA + 2] = v.z; tile[r][cA + 3] = v.w;
  }
  __syncthreads();
#pragma unroll
  for (int rr = 0; rr < 4; ++rr) {
    int c = rr * 16 + rA;
    u16x4 o = {f2bf(tile[cA][c]), f2bf(tile[cA + 1][c]), f2bf(tile[cA + 2][c]),
               f2bf(tile[cA + 3][c])};
    *(u16x4*)(out + (c0 + c) * 1024 + r0 + cA) = o;
  }
}

// ---------- GEMM: C[M,N] = A[M,K] @ Bt[N,K]^T  (bf16 in, f32 acc) ----------
// 128x128 tile, BK=64, 4 waves. T3-minimum 2-phase pipeline: stage(t+1) issued
// BEFORE compute(t); one vmcnt-draining barrier per K-step.
template <int F32OUT>
__global__ __launch_bounds__(256) void gemm_bt(const u16* __restrict__ A,
                                               const u16* __restrict__ Bt,
                                               u16* __restrict__ Cb,
                                               float* __restrict__ Cf,
                                               const float* __restrict__ bias,
                                               int M, int N, int K) {
  __shared__ alignas(16) u16 As[2][128 * 64];
  __shared__ alignas(16) u16 Bs[2][128 * 64];
  const int tid = threadIdx.x;
  const int lane = tid & 63, w = tid >> 6;
  const int wr = w >> 1, wc = w & 1;
  const int g = lane >> 4, c15 = lane & 15;
  const int nbk = N >> 7;
  const int bm = blockIdx.x / nbk, bn = blockIdx.x % nbk;

  f32x4 acc[4][4] = {};

  const int srow = tid >> 3;        // 0..31 (+ i*32)
  const int scol = (tid & 7) * 8;   // 0..56
  const u16* Ag = A + (bm * 128 + srow) * K + scol;
  const u16* Bg = Bt + (bn * 128 + srow) * K + scol;
  const int lds_e = tid * 8;        // + i*2048

  auto stage = [&](int kt, int buf) {
#pragma unroll
    for (int i = 0; i < 4; ++i) GLOAD_LDS16(Ag + i * 32 * K + kt, &As[buf][lds_e + i * 2048]);
#pragma unroll
    for (int i = 0; i < 4; ++i) GLOAD_LDS16(Bg + i * 32 * K + kt, &Bs[buf][lds_e + i * 2048]);
  };

  stage(0, 0);
  __syncthreads();

  const int nkt = K >> 6;
  for (int t = 0; t < nkt; ++t) {
    const int c = t & 1;
    if (t + 1 < nkt) stage((t + 1) << 6, c ^ 1);
#pragma unroll
    for (int kc = 0; kc < 2; ++kc) {
      s16x8 a[4], b[4];
#pragma unroll
      for (int mb = 0; mb < 4; ++mb)
        a[mb] = *(const s16x8*)&As[c][(wr * 64 + mb * 16 + c15) * 64 + kc * 32 + g * 8];
#pragma unroll
      for (int nb = 0; nb < 4; ++nb)
        b[nb] = *(const s16x8*)&Bs[c][(wc * 64 + nb * 16 + c15) * 64 + kc * 32 + g * 8];
#pragma unroll
      for (int mb = 0; mb < 4; ++mb)
#pragma unroll
        for (int nb = 0; nb < 4; ++nb) acc[mb][nb] = mfma16(a[mb], b[nb], acc[mb][nb]);
    }
    __syncthreads();  // publishes buf c^1 (vmcnt drained here, hidden by compute)
  }
#pragma unroll
  for (int mb = 0; mb < 4; ++mb) {
#pragma unroll
    for (int nb = 0; nb < 4; ++nb) {
      int row0 = bm * 128 + wr * 64 + mb * 16 + g * 4;
      int col = bn * 128 + wc * 64 + nb * 16 + c15;
#pragma unroll
      for (int r = 0; r < 4; ++r) {
        float v = acc[mb][nb][r];
        if (F32OUT)
          Cf[(row0 + r) * N + col] = v + bias[col];
        else
          Cb[(row0 + r) * N + col] = f2bf(v);
      }
    }
  }
}

// ---------- flash attention (dbuf + swapped QK^T + defer-rescale) ----------
// QKV [4096][3072] bf16 (row = b*2048+t, col = qkv*1024 + h*64 + d)
// AO: torch-raw-reshape layout: AO[(2h+b)*131072 + t*64 + d]  (as [4096][1024])
// Grid: (32 q-blocks of 64 rows, 32 b*h) = 1024 blocks -> 4 blocks/CU.
// 4 waves/block, 16 q-rows/wave. LDS 40KB -> exactly 4 blocks/CU.
__global__ __launch_bounds__(256, 4) void attn_fwd(const u16* __restrict__ QKV,
                                                   u16* __restrict__ AO) {
  __shared__ alignas(16) u16 Ks[2][64 * 64];   // [key][d] swizzled
  __shared__ alignas(16) u16 Vt[2][64 * 64];   // [d][key] swizzled
  __shared__ alignas(16) u16 Ps[4][16 * 64];   // per-wave P [q][key] swizzled
  const int tid = threadIdx.x, lane = tid & 63, w = tid >> 6;
  const int qb = blockIdx.x;       // 0..31
  const int bh = blockIdx.y;       // 0..31
  const int h = bh >> 1, b = bh & 1;
  const int g = lane >> 4, c15 = lane & 15;
  const int bt0 = b * 2048;
  const float CS = 0.125f * LOG2E;  // scale folded with log2e

  // Q fragments (stay in regs): wave's rows = qb*64 + w*16 + c15
  s16x8 q[2];
#pragma unroll
  for (int kc = 0; kc < 2; ++kc) {
    int row = bt0 + qb * 64 + w * 16 + c15;
    q[kc] = *(const s16x8*)&QKV[row * 3072 + h * 64 + kc * 32 + g * 8];
  }

  f32x4 o[4] = {};
  float mrow = -1e30f, lrow = 0.f;  // per-lane: q-row = c15 (replicated over g)

  const int skey = tid >> 3;        // 0..31 (+ i*32)
  const int schunk = tid & 7;       // 16B chunk index within 128B row
  const u16* Vg = QKV + (bt0 + skey) * 3072 + 2048 + h * 64 + schunk * 8;

  // K stage: linear LDS dest, pre-swizzled global source (both-sides rule)
  auto stageK = [&](int key0, int buf) {
#pragma unroll
    for (int i = 0; i < 2; ++i) {
      int key = skey + i * 32;
      int s7 = (key & 7) ^ ((key >> 3) & 7);
      const u16* src =
          QKV + (bt0 + key0 + key) * 3072 + 1024 + h * 64 + ((schunk ^ s7) * 8);
      GLOAD_LDS16(src, &Ks[buf][tid * 8 + i * 2048]);
    }
  };
  auto writeV = [&](const s16x8* v, int buf) {
#pragma unroll
    for (int i = 0; i < 2; ++i) {
      int key = skey + i * 32;
#pragma unroll
      for (int j = 0; j < 8; ++j) {
        int d = schunk * 8 + j;
        Vt[buf][d * 64 + (key ^ swzm(d))] = (u16)v[i][j];
      }
    }
  };

  // prologue: stage tile 0 into buf 0
  {
    stageK(0, 0);
    s16x8 v0[2];
    v0[0] = *(const s16x8*)(Vg + 0 * 3072);
    v0[1] = *(const s16x8*)(Vg + 32 * 3072);
    writeV(v0, 0);
  }
  __syncthreads();

  for (int t = 0; t < 32; ++t) {
    const int c = t & 1;
    const int key0 = t * 64;
    const bool more = (t < 31);
    s16x8 vn[2];
    if (more) {
      stageK(key0 + 64, c ^ 1);
      vn[0] = *(const s16x8*)(Vg + (key0 + 64) * 3072);
      vn[1] = *(const s16x8*)(Vg + (key0 + 96) * 3072);
    }

    // S^T = K Q^T: s[nb] lane holds S[key=nb*16+g*4+r][q=c15]
    f32x4 s[4] = {};
    __builtin_amdgcn_s_setprio(1);
#pragma unroll
    for (int kc = 0; kc < 2; ++kc) {
      s16x8 kf[4];
#pragma unroll
      for (int nb = 0; nb < 4; ++nb) {
        int row = nb * 16 + c15;
        kf[nb] = *(const s16x8*)&Ks[c][row * 64 + ((kc * 32 + g * 8) ^ swzm(row))];
      }
#pragma unroll
      for (int nb = 0; nb < 4; ++nb) s[nb] = mfma16(kf[nb], q[kc], s[nb]);
    }
    __builtin_amdgcn_s_setprio(0);

    // softmax: per lane one q-row (c15), 16 in-lane keys + 2 shfl cross-group
#pragma unroll
    for (int nb = 0; nb < 4; ++nb)
#pragma unroll
      for (int r = 0; r < 4; ++r) s[nb][r] *= CS;
    float m01 = fmaxf(fmaxf(s[0][0], s[0][1]), fmaxf(s[0][2], s[0][3]));
    float m11 = fmaxf(fmaxf(s[1][0], s[1][1]), fmaxf(s[1][2], s[1][3]));
    float m21 = fmaxf(fmaxf(s[2][0], s[2][1]), fmaxf(s[2][2], s[2][3]));
    float m31 = fmaxf(fmaxf(s[3][0], s[3][1]), fmaxf(s[3][2], s[3][3]));
    float m0 = fmaxf(fmaxf(m01, m11), fmaxf(m21, m31));
    m0 = fmaxf(m0, __shfl_xor(m0, 16, 64));
    m0 = fmaxf(m0, __shfl_xor(m0, 32, 64));
    bool exceed = (m0 > mrow + 8.0f);
    if (__any(exceed)) {  // rescale (rare after warm-up)
      float mn = fmaxf(mrow, m0);
      float alpha = exp2f(mrow - mn);
      mrow = mn;
      lrow *= alpha;
#pragma unroll
      for (int r = 0; r < 4; ++r) {
        float aB = __shfl(alpha, g * 4 + r, 64);  // c15-domain -> row-domain
#pragma unroll
        for (int db = 0; db < 4; ++db) o[db][r] *= aB;
      }
    }
    {
      float m = mrow;
#pragma unroll
      for (int nb = 0; nb < 4; ++nb)
#pragma unroll
        for (int r = 0; r < 4; ++r) s[nb][r] = exp2f(s[nb][r] - m);
      float s0 = (s[0][0] + s[0][1]) + (s[0][2] + s[0][3]);
      float s1 = (s[1][0] + s[1][1]) + (s[1][2] + s[1][3]);
      float s2 = (s[2][0] + s[2][1]) + (s[2][2] + s[2][3]);
      float s3 = (s[3][0] + s[3][1]) + (s[3][2] + s[3][3]);
      float rs = (s0 + s1) + (s2 + s3);
      rs += __shfl_xor(rs, 16, 64);
      rs += __shfl_xor(rs, 32, 64);
      lrow += rs;
      // P write: 4 consecutive keys (r=0..3) -> one b64 per nb
      int row = c15;
#pragma unroll
      for (int nb = 0; nb < 4; ++nb) {
        u16x4 pk = {f2bf(s[nb][0]), f2bf(s[nb][1]), f2bf(s[nb][2]), f2bf(s[nb][3])};
        *(u16x4*)&Ps[w][row * 64 + ((nb * 16 + g * 4) ^ swzm(row))] = pk;
      }
    }

    // O += P @ V (unswapped; o rows = q = g*4+r, cols = d = db*16+c15)
    __builtin_amdgcn_s_setprio(1);
#pragma unroll
    for (int kc = 0; kc < 2; ++kc) {
      s16x8 pf, vf[4];
      {
        int row = c15;
        pf = *(const s16x8*)&Ps[w][row * 64 + ((kc * 32 + g * 8) ^ swzm(row))];
      }
#pragma unroll
      for (int db = 0; db < 4; ++db) {
        int row = db * 16 + c15;
        vf[db] = *(const s16x8*)&Vt[c][row * 64 + ((kc * 32 + g * 8) ^ swzm(row))];
      }
#pragma unroll
      for (int db = 0; db < 4; ++db) o[db] = mfma16(pf, vf[db], o[db]);
    }
    __builtin_amdgcn_s_setprio(0);

    // T14 write-late: V(t+1) reg->LDS just before the barrier
    if (more) writeV(vn, c ^ 1);
    __syncthreads();  // publishes buf c^1 (K via vmcnt drain, V via lgkm drain)
  }

  // epilogue: O / l (broadcast lrow c15-domain -> row-domain), torch-raw layout
#pragma unroll
  for (int r = 0; r < 4; ++r) {
    float lB = __shfl(lrow, g * 4 + r, 64);
    float rinv = 1.0f / lB;
    int trow = qb * 64 + w * 16 + g * 4 + r;
#pragma unroll
    for (int db = 0; db < 4; ++db)
      AO[(2 * h + b) * 131072 + trow * 64 + db * 16 + c15] = f2bf(o[db][r] * rinv);
  }
}

// ---------- launch ----------
extern "C" void kernel_launch(void* const* d_in, const int* in_sizes, int n_in,
                              void* d_out, int out_size, void* d_ws, size_t ws_size,
                              hipStream_t stream) {
  const float* x = (const float*)d_in[0];
  const float* Wq = (const float*)d_in[1];
  const float* Wk = (const float*)d_in[2];
  const float* Wv = (const float*)d_in[3];
  const float* Wp = (const float*)d_in[4];
  const float* bp = (const float*)d_in[5];
  float* out = (float*)d_out;

  u16* Xb = (u16*)d_ws;                   // [4096][1024]
  u16* Wt = Xb + 4096 * 1024;             // [3072][1024]
  u16* WpT = Wt + 3072 * 1024;            // [1024][1024]
  u16* QKV = WpT + 1024 * 1024;           // [4096][3072]
  u16* AO = QKV + 4096 * 3072;            // [4096][1024]

  k_cast_bf16<<<4096, 256, 0, stream>>>(x, Xb);
  k_wqkv<<<dim3(16, 48), 256, 0, stream>>>(Wq, Wk, Wv, Wt);
  k_wp<<<dim3(16, 16), 256, 0, stream>>>(Wp, WpT);
  gemm_bt<0><<<dim3(32 * 24), 256, 0, stream>>>(Xb, Wt, QKV, nullptr, nullptr, 4096, 3072, 1024);
  attn_fwd<<<dim3(32, 32), 256, 0, stream>>>(QKV, AO);
  gemm_bt<1><<<dim3(32 * 8), 256, 0, stream>>>(AO, WpT, nullptr, out, bp, 4096, 1024, 1024);
}

// Round 7
// 249.351 us; speedup vs baseline: 1.0132x; 1.0132x over previous
//
#include <hip/hip_runtime.h>

// ---------- types ----------
typedef unsigned short u16;
typedef __attribute__((ext_vector_type(4))) float f32x4;
typedef __attribute__((ext_vector_type(8))) short s16x8;
typedef __attribute__((ext_vector_type(8))) __bf16 bf16x8;
typedef __attribute__((ext_vector_type(4))) unsigned short u16x4;

#define LOG2E 1.44269504088896340736f

__device__ __forceinline__ u16 f2bf(float f) {
  unsigned u = __builtin_bit_cast(unsigned, f);
  u += 0x7fffu + ((u >> 16) & 1u);  // RNE
  return (u16)(u >> 16);
}

__device__ __forceinline__ f32x4 mfma16(s16x8 a, s16x8 b, f32x4 c) {
  return __builtin_amdgcn_mfma_f32_16x16x32_bf16(
      __builtin_bit_cast(bf16x8, a), __builtin_bit_cast(bf16x8, b), c, 0, 0, 0);
}

// XOR-swizzle mask for u16-indexed rows of 64 elems (128B): flips idx bits 3..5.
__device__ __forceinline__ int swzm(int row) {
  return (((row & 7) ^ ((row >> 3) & 7)) << 3);
}

// global -> LDS direct copy, 16B per lane. LDS dest must be uniform-base + lane*16.
#define GLOAD_LDS16(g, l)                                                      \
  __builtin_amdgcn_global_load_lds(                                            \
      (const __attribute__((address_space(1))) unsigned int*)(g),              \
      (__attribute__((address_space(3))) unsigned int*)(l), 16, 0, 0)

// ---------- cast x f32 -> bf16 (4 elems/thread, exact grid) ----------
__global__ __launch_bounds__(256) void k_cast_bf16(const float* __restrict__ in,
                                                   u16* __restrict__ out) {
  int i = (blockIdx.x * 256 + threadIdx.x) * 4;
  float4 v = *(const float4*)(in + i);
  u16x4 o = {f2bf(v.x), f2bf(v.y), f2bf(v.z), f2bf(v.w)};
  *(u16x4*)(out + i) = o;
}

// ---------- Wq/Wk/Wv [H,C,D] f32 -> Wt [3*H*D][C] bf16 (B^T layout) ----------
__global__ __launch_bounds__(256) void k_wqkv(const float* __restrict__ Wq,
                                              const float* __restrict__ Wk,
                                              const float* __restrict__ Wv,
                                              u16* __restrict__ Wt) {
  int z = blockIdx.y;  // 0..47
  int qkv = z >> 4, h = z & 15;
  const float* in = (qkv == 0 ? Wq : (qkv == 1 ? Wk : Wv)) + h * 1024 * 64;
  int c0 = blockIdx.x * 64;
  __shared__ float tile[64][65];
  int t = threadIdx.x;
  int rA = t >> 4, cA = (t & 15) * 4;
#pragma unroll
  for (int rr = 0; rr < 4; ++rr) {
    int c = rr * 16 + rA;
    float4 v = *(const float4*)(in + (c0 + c) * 64 + cA);
    tile[c][cA] = v.x; tile[c][cA + 1] = v.y; tile[c][cA + 2] = v.z; tile[c][cA + 3] = v.w;
  }
  __syncthreads();
  int obase = qkv * 1024 + h * 64;
#pragma unroll
  for (int rr = 0; rr < 4; ++rr) {
    int d = rr * 16 + rA;
    u16x4 o = {f2bf(tile[cA][d]), f2bf(tile[cA + 1][d]), f2bf(tile[cA + 2][d]),
               f2bf(tile[cA + 3][d])};
    *(u16x4*)(Wt + (obase + d) * 1024 + c0 + cA) = o;
  }
}

// ---------- Wp [1024][1024] f32 -> WpT [n][k] bf16 ----------
__global__ __launch_bounds__(256) void k_wp(const float* __restrict__ in,
                                            u16* __restrict__ out) {
  int r0 = blockIdx.y * 64, c0 = blockIdx.x * 64;
  __shared__ float tile[64][65];
  int t = threadIdx.x;
  int rA = t >> 4, cA = (t & 15) * 4;
#pragma unroll
  for (int rr = 0; rr < 4; ++rr) {
    int r = rr * 16 + rA;
    float4 v = *(const float4*)(in + (r0 + r) * 1024 + c0 + cA);
    tile[r][cA] = v.x; tile[r][cA + 1] = v.y; tile[r][cA + 2] = v.z; tile[r][cA + 3] = v.w;
  }
  __syncthreads();
#pragma unroll
  for (int rr = 0; rr < 4; ++rr) {
    int c = rr * 16 + rA;
    u16x4 o = {f2bf(tile[cA][c]), f2bf(tile[cA + 1][c]), f2bf(tile[cA + 2][c]),
               f2bf(tile[cA + 3][c])};
    *(u16x4*)(out + (c0 + c) * 1024 + r0 + cA) = o;
  }
}

// ---------- V-part of QKV -> Vtg[(b*16+h)*64+d][t] (global V^T) ----------
// One 64t x 64d tile per block. Coalesced loads (t-rows) and stores (d-rows).
__global__ __launch_bounds__(256) void k_vt(const u16* __restrict__ QKV,
                                            u16* __restrict__ Vtg) {
  const int bh = blockIdx.y;  // b*16+h
  const int b = bh >> 4, h = bh & 15;
  const int t0 = blockIdx.x * 64;
  __shared__ u16 tile[64][65];
  const int tid = threadIdx.x;
  const int tr = tid >> 3, ch = tid & 7;
#pragma unroll
  for (int i = 0; i < 2; ++i) {
    int t = tr + i * 32;
    s16x8 v = *(const s16x8*)&QKV[(b * 2048 + t0 + t) * 3072 + 2048 + h * 64 + ch * 8];
#pragma unroll
    for (int j = 0; j < 8; ++j) tile[t][ch * 8 + j] = (u16)v[j];
  }
  __syncthreads();
#pragma unroll
  for (int i = 0; i < 2; ++i) {
    int d = tr + i * 32;
    s16x8 o;
#pragma unroll
    for (int j = 0; j < 8; ++j) o[j] = (short)tile[ch * 8 + j][d];
    *(s16x8*)&Vtg[(bh * 64 + d) * 2048 + t0 + ch * 8] = o;
  }
}

// ---------- GEMM: C[M,N] = A[M,K] @ Bt[N,K]^T  (bf16 in, f32 acc) ----------
// 128x128 tile, BK=64, 4 waves. 2-phase pipeline: stage(t+1) before compute(t).
template <int F32OUT>
__global__ __launch_bounds__(256) void gemm_bt(const u16* __restrict__ A,
                                               const u16* __restrict__ Bt,
                                               u16* __restrict__ Cb,
                                               float* __restrict__ Cf,
                                               const float* __restrict__ bias,
                                               int M, int N, int K) {
  __shared__ alignas(16) u16 As[2][128 * 64];
  __shared__ alignas(16) u16 Bs[2][128 * 64];
  const int tid = threadIdx.x;
  const int lane = tid & 63, w = tid >> 6;
  const int wr = w >> 1, wc = w & 1;
  const int g = lane >> 4, c15 = lane & 15;
  const int nbk = N >> 7;
  const int bm = blockIdx.x / nbk, bn = blockIdx.x % nbk;

  f32x4 acc[4][4] = {};

  const int srow = tid >> 3;        // 0..31 (+ i*32)
  const int scol = (tid & 7) * 8;   // 0..56
  const u16* Ag = A + (bm * 128 + srow) * K + scol;
  const u16* Bg = Bt + (bn * 128 + srow) * K + scol;
  const int lds_e = tid * 8;        // + i*2048

  auto stage = [&](int kt, int buf) {
#pragma unroll
    for (int i = 0; i < 4; ++i) GLOAD_LDS16(Ag + i * 32 * K + kt, &As[buf][lds_e + i * 2048]);
#pragma unroll
    for (int i = 0; i < 4; ++i) GLOAD_LDS16(Bg + i * 32 * K + kt, &Bs[buf][lds_e + i * 2048]);
  };

  stage(0, 0);
  __syncthreads();

  const int nkt = K >> 6;
  for (int t = 0; t < nkt; ++t) {
    const int c = t & 1;
    if (t + 1 < nkt) stage((t + 1) << 6, c ^ 1);
#pragma unroll
    for (int kc = 0; kc < 2; ++kc) {
      s16x8 a[4], b[4];
#pragma unroll
      for (int mb = 0; mb < 4; ++mb)
        a[mb] = *(const s16x8*)&As[c][(wr * 64 + mb * 16 + c15) * 64 + kc * 32 + g * 8];
#pragma unroll
      for (int nb = 0; nb < 4; ++nb)
        b[nb] = *(const s16x8*)&Bs[c][(wc * 64 + nb * 16 + c15) * 64 + kc * 32 + g * 8];
#pragma unroll
      for (int mb = 0; mb < 4; ++mb)
#pragma unroll
        for (int nb = 0; nb < 4; ++nb) acc[mb][nb] = mfma16(a[mb], b[nb], acc[mb][nb]);
    }
    __syncthreads();  // publishes buf c^1 (vmcnt drained here, hidden by compute)
  }
#pragma unroll
  for (int mb = 0; mb < 4; ++mb) {
#pragma unroll
    for (int nb = 0; nb < 4; ++nb) {
      int row0 = bm * 128 + wr * 64 + mb * 16 + g * 4;
      int col = bn * 128 + wc * 64 + nb * 16 + c15;
#pragma unroll
      for (int r = 0; r < 4; ++r) {
        float v = acc[mb][nb][r];
        if (F32OUT)
          Cf[(row0 + r) * N + col] = v + bias[col];
        else
          Cb[(row0 + r) * N + col] = f2bf(v);
      }
    }
  }
}

// ---------- flash attention ----------
// QKV [4096][3072] bf16 (row = b*2048+t, col = qkv*1024 + h*64 + d)
// Vtg [(b*16+h)*64+d][2048] bf16 (global V^T) — NOTE writer order is b*16+h!
// AO: torch-raw-reshape layout: AO[(2h+b)*131072 + t*64 + d]  (as [4096][1024])
// Grid: 512 blocks x 512 threads (8 waves, 16 q-rows each -> 128 q-rows/block).
// XCD swizzle: wgid=(bid&7)*64+(bid>>3) -> 4 bh per XCD (K/V 2MB <= 4MB L2).
// K AND V staged via global_load_lds (no in-kernel transpose); both swizzled
// via pre-permuted global source (both-sides rule).
__global__ __launch_bounds__(512, 4) void attn_fwd(const u16* __restrict__ QKV,
                                                   const u16* __restrict__ Vtg,
                                                   u16* __restrict__ AO) {
  __shared__ alignas(16) u16 Ks[2][64 * 64];   // [key][d] swizzled
  __shared__ alignas(16) u16 Vt[2][64 * 64];   // [d][key] swizzled
  __shared__ alignas(16) u16 Ps[8][16 * 64];   // per-wave P [q][key] swizzled
  const int tid = threadIdx.x, lane = tid & 63, w = tid >> 6;
  const int bid = blockIdx.x;
  const int wgid = (bid & 7) * 64 + (bid >> 3);  // bijective XCD clustering
  const int qb = wgid & 15;        // 0..15 (128 q-rows each)
  const int bh = wgid >> 4;        // 0..31 (= 2h+b, AO order)
  const int h = bh >> 1, b = bh & 1;
  const int g = lane >> 4, c15 = lane & 15;
  const int bt0 = b * 2048;
  const float CS = 0.125f * LOG2E;  // scale folded with log2e

  // Q fragments (stay in regs): wave's rows = qb*128 + w*16 + c15
  s16x8 q[2];
#pragma unroll
  for (int kc = 0; kc < 2; ++kc) {
    int row = bt0 + qb * 128 + w * 16 + c15;
    q[kc] = *(const s16x8*)&QKV[row * 3072 + h * 64 + kc * 32 + g * 8];
  }

  f32x4 o[4] = {};
  float mrow = -1e30f, lrow = 0.f;  // per-lane: q-row = c15 (replicated over g)

  // staging indices (512 threads, one 16B chunk each per tile)
  const int srow = tid >> 3;        // 0..63 (key for K-stage, d for V-stage)
  const int sch = tid & 7;          // chunk 0..7
  const int ss7 = (srow & 7) ^ ((srow >> 3) & 7);
  const u16* Kg = QKV + (bt0 + srow) * 3072 + 1024 + h * 64 + ((sch ^ ss7) * 8);
  // Vtg row-block index uses the WRITER's ordering: b*16 + h  (bug fixed)
  const u16* Vgt = Vtg + ((b * 16 + h) * 64 + srow) * 2048 + ((sch ^ ss7) * 8);

  auto stageKV = [&](int key0, int buf) {
    GLOAD_LDS16(Kg + key0 * 3072, &Ks[buf][tid * 8]);
    GLOAD_LDS16(Vgt + key0, &Vt[buf][tid * 8]);
  };

  stageKV(0, 0);
  __syncthreads();

  for (int t = 0; t < 32; ++t) {
    const int c = t & 1;
    if (t < 31) stageKV((t + 1) * 64, c ^ 1);

    // S^T = K Q^T: s[nb] lane holds S[key=nb*16+g*4+r][q=c15]
    f32x4 s[4] = {};
    __builtin_amdgcn_s_setprio(1);
#pragma unroll
    for (int kc = 0; kc < 2; ++kc) {
      s16x8 kf[4];
#pragma unroll
      for (int nb = 0; nb < 4; ++nb) {
        int row = nb * 16 + c15;
        kf[nb] = *(const s16x8*)&Ks[c][row * 64 + ((kc * 32 + g * 8) ^ swzm(row))];
      }
#pragma unroll
      for (int nb = 0; nb < 4; ++nb) s[nb] = mfma16(kf[nb], q[kc], s[nb]);
    }
    __builtin_amdgcn_s_setprio(0);

    // softmax: per lane one q-row (c15), 16 in-lane keys + 2 shfl cross-group
#pragma unroll
    for (int nb = 0; nb < 4; ++nb)
#pragma unroll
      for (int r = 0; r < 4; ++r) s[nb][r] *= CS;
    float m01 = fmaxf(fmaxf(s[0][0], s[0][1]), fmaxf(s[0][2], s[0][3]));
    float m11 = fmaxf(fmaxf(s[1][0], s[1][1]), fmaxf(s[1][2], s[1][3]));
    float m21 = fmaxf(fmaxf(s[2][0], s[2][1]), fmaxf(s[2][2], s[2][3]));
    float m31 = fmaxf(fmaxf(s[3][0], s[3][1]), fmaxf(s[3][2], s[3][3]));
    float m0 = fmaxf(fmaxf(m01, m11), fmaxf(m21, m31));
    m0 = fmaxf(m0, __shfl_xor(m0, 16, 64));
    m0 = fmaxf(m0, __shfl_xor(m0, 32, 64));
    bool exceed = (m0 > mrow + 8.0f);
    if (__any(exceed)) {  // rescale (rare after warm-up)
      float mn = fmaxf(mrow, m0);
      float alpha = exp2f(mrow - mn);
      mrow = mn;
      lrow *= alpha;
#pragma unroll
      for (int r = 0; r < 4; ++r) {
        float aB = __shfl(alpha, g * 4 + r, 64);  // c15-domain -> row-domain
#pragma unroll
        for (int db = 0; db < 4; ++db) o[db][r] *= aB;
      }
    }
    {
      float m = mrow;
#pragma unroll
      for (int nb = 0; nb < 4; ++nb)
#pragma unroll
        for (int r = 0; r < 4; ++r) s[nb][r] = exp2f(s[nb][r] - m);
      float s0 = (s[0][0] + s[0][1]) + (s[0][2] + s[0][3]);
      float s1 = (s[1][0] + s[1][1]) + (s[1][2] + s[1][3]);
      float s2 = (s[2][0] + s[2][1]) + (s[2][2] + s[2][3]);
      float s3 = (s[3][0] + s[3][1]) + (s[3][2] + s[3][3]);
      float rs = (s0 + s1) + (s2 + s3);
      rs += __shfl_xor(rs, 16, 64);
      rs += __shfl_xor(rs, 32, 64);
      lrow += rs;
      // P write: 4 consecutive keys (r=0..3) -> one b64 per nb
      int row = c15;
#pragma unroll
      for (int nb = 0; nb < 4; ++nb) {
        u16x4 pk = {f2bf(s[nb][0]), f2bf(s[nb][1]), f2bf(s[nb][2]), f2bf(s[nb][3])};
        *(u16x4*)&Ps[w][row * 64 + ((nb * 16 + g * 4) ^ swzm(row))] = pk;
      }
    }

    // O += P @ V (o rows = q = g*4+r, cols = d = db*16+c15)
    __builtin_amdgcn_s_setprio(1);
#pragma unroll
    for (int kc = 0; kc < 2; ++kc) {
      s16x8 pf, vf[4];
      {
        int row = c15;
        pf = *(const s16x8*)&Ps[w][row * 64 + ((kc * 32 + g * 8) ^ swzm(row))];
      }
#pragma unroll
      for (int db = 0; db < 4; ++db) {
        int row = db * 16 + c15;
        vf[db] = *(const s16x8*)&Vt[c][row * 64 + ((kc * 32 + g * 8) ^ swzm(row))];
      }
#pragma unroll
      for (int db = 0; db < 4; ++db) o[db] = mfma16(pf, vf[db], o[db]);
    }
    __builtin_amdgcn_s_setprio(0);

    __syncthreads();  // publishes buf c^1 (vmcnt drain hidden by compute)
  }

  // epilogue: O / l (broadcast lrow c15-domain -> row-domain), torch-raw layout
#pragma unroll
  for (int r = 0; r < 4; ++r) {
    float lB = __shfl(lrow, g * 4 + r, 64);
    float rinv = 1.0f / lB;
    int trow = qb * 128 + w * 16 + g * 4 + r;
#pragma unroll
    for (int db = 0; db < 4; ++db)
      AO[(2 * h + b) * 131072 + trow * 64 + db * 16 + c15] = f2bf(o[db][r] * rinv);
  }
}

// ---------- launch ----------
extern "C" void kernel_launch(void* const* d_in, const int* in_sizes, int n_in,
                              void* d_out, int out_size, void* d_ws, size_t ws_size,
                              hipStream_t stream) {
  const float* x = (const float*)d_in[0];
  const float* Wq = (const float*)d_in[1];
  const float* Wk = (const float*)d_in[2];
  const float* Wv = (const float*)d_in[3];
  const float* Wp = (const float*)d_in[4];
  const float* bp = (const float*)d_in[5];
  float* out = (float*)d_out;

  u16* Xb = (u16*)d_ws;                   // [4096][1024]  (reused as Vtg later)
  u16* Wt = Xb + 4096 * 1024;             // [3072][1024]
  u16* WpT = Wt + 3072 * 1024;            // [1024][1024]
  u16* QKV = WpT + 1024 * 1024;           // [4096][3072]
  u16* AO = QKV + 4096 * 3072;            // [4096][1024]
  u16* Vtg = Xb;                          // [32*64][2048] — Xb dead after gemm1

  k_cast_bf16<<<4096, 256, 0, stream>>>(x, Xb);
  k_wqkv<<<dim3(16, 48), 256, 0, stream>>>(Wq, Wk, Wv, Wt);
  k_wp<<<dim3(16, 16), 256, 0, stream>>>(Wp, WpT);
  gemm_bt<0><<<dim3(32 * 24), 256, 0, stream>>>(Xb, Wt, QKV, nullptr, nullptr, 4096, 3072, 1024);
  k_vt<<<dim3(32, 32), 256, 0, stream>>>(QKV, Vtg);
  attn_fwd<<<512, 512, 0, stream>>>(QKV, Vtg, AO);
  gemm_bt<1><<<dim3(32 * 8), 256, 0, stream>>>(AO, WpT, nullptr, out, bp, 4096, 1024, 1024);
}

// Round 8
// 238.960 us; speedup vs baseline: 1.0572x; 1.0435x over previous
//
#include <hip/hip_runtime.h>

// ---------- types ----------
typedef unsigned short u16;
typedef __attribute__((ext_vector_type(4))) float f32x4;
typedef __attribute__((ext_vector_type(8))) short s16x8;
typedef __attribute__((ext_vector_type(8))) __bf16 bf16x8;
typedef __attribute__((ext_vector_type(4))) __bf16 bf16x4;
typedef __attribute__((ext_vector_type(4))) unsigned short u16x4;

#define LOG2E 1.44269504088896340736f

__device__ __forceinline__ u16 f2bf(float f) {
  unsigned u = __builtin_bit_cast(unsigned, f);
  u += 0x7fffu + ((u >> 16) & 1u);  // RNE
  return (u16)(u >> 16);
}

__device__ __forceinline__ f32x4 mfma16(s16x8 a, s16x8 b, f32x4 c) {
  return __builtin_amdgcn_mfma_f32_16x16x32_bf16(
      __builtin_bit_cast(bf16x8, a), __builtin_bit_cast(bf16x8, b), c, 0, 0, 0);
}

// XOR-swizzle mask for u16-indexed rows of 64 elems (128B): flips idx bits 3..5.
__device__ __forceinline__ int swzm(int row) {
  return (((row & 7) ^ ((row >> 3) & 7)) << 3);
}

// global -> LDS direct copy, 16B per lane. LDS dest must be uniform-base + lane*16.
#define GLOAD_LDS16(g, l)                                                      \
  __builtin_amdgcn_global_load_lds(                                            \
      (const __attribute__((address_space(1))) unsigned int*)(g),              \
      (__attribute__((address_space(3))) unsigned int*)(l), 16, 0, 0)

// ---------- cast x f32 -> bf16 (4 elems/thread, exact grid) ----------
__global__ __launch_bounds__(256) void k_cast_bf16(const float* __restrict__ in,
                                                   u16* __restrict__ out) {
  int i = (blockIdx.x * 256 + threadIdx.x) * 4;
  float4 v = *(const float4*)(in + i);
  u16x4 o = {f2bf(v.x), f2bf(v.y), f2bf(v.z), f2bf(v.w)};
  *(u16x4*)(out + i) = o;
}

// ---------- Wq/Wk/Wv [H,C,D] f32 -> Wt [3*H*D][C] bf16 (B^T layout) ----------
__global__ __launch_bounds__(256) void k_wqkv(const float* __restrict__ Wq,
                                              const float* __restrict__ Wk,
                                              const float* __restrict__ Wv,
                                              u16* __restrict__ Wt) {
  int z = blockIdx.y;  // 0..47
  int qkv = z >> 4, h = z & 15;
  const float* in = (qkv == 0 ? Wq : (qkv == 1 ? Wk : Wv)) + h * 1024 * 64;
  int c0 = blockIdx.x * 64;
  __shared__ float tile[64][65];
  int t = threadIdx.x;
  int rA = t >> 4, cA = (t & 15) * 4;
#pragma unroll
  for (int rr = 0; rr < 4; ++rr) {
    int c = rr * 16 + rA;
    float4 v = *(const float4*)(in + (c0 + c) * 64 + cA);
    tile[c][cA] = v.x; tile[c][cA + 1] = v.y; tile[c][cA + 2] = v.z; tile[c][cA + 3] = v.w;
  }
  __syncthreads();
  int obase = qkv * 1024 + h * 64;
#pragma unroll
  for (int rr = 0; rr < 4; ++rr) {
    int d = rr * 16 + rA;
    u16x4 o = {f2bf(tile[cA][d]), f2bf(tile[cA + 1][d]), f2bf(tile[cA + 2][d]),
               f2bf(tile[cA + 3][d])};
    *(u16x4*)(Wt + (obase + d) * 1024 + c0 + cA) = o;
  }
}

// ---------- Wp [1024][1024] f32 -> WpT [n][k] bf16 ----------
__global__ __launch_bounds__(256) void k_wp(const float* __restrict__ in,
                                            u16* __restrict__ out) {
  int r0 = blockIdx.y * 64, c0 = blockIdx.x * 64;
  __shared__ float tile[64][65];
  int t = threadIdx.x;
  int rA = t >> 4, cA = (t & 15) * 4;
#pragma unroll
  for (int rr = 0; rr < 4; ++rr) {
    int r = rr * 16 + rA;
    float4 v = *(const float4*)(in + (r0 + r) * 1024 + c0 + cA);
    tile[r][cA] = v.x; tile[r][cA + 1] = v.y; tile[r][cA + 2] = v.z; tile[r][cA + 3] = v.w;
  }
  __syncthreads();
#pragma unroll
  for (int rr = 0; rr < 4; ++rr) {
    int c = rr * 16 + rA;
    u16x4 o = {f2bf(tile[cA][c]), f2bf(tile[cA + 1][c]), f2bf(tile[cA + 2][c]),
               f2bf(tile[cA + 3][c])};
    *(u16x4*)(out + (c0 + c) * 1024 + r0 + cA) = o;
  }
}

// ---------- V-part of QKV -> Vtg[(b*16+h)*64+d][t] (global V^T) ----------
__global__ __launch_bounds__(256) void k_vt(const u16* __restrict__ QKV,
                                            u16* __restrict__ Vtg) {
  const int bh = blockIdx.y;  // b*16+h
  const int b = bh >> 4, h = bh & 15;
  const int t0 = blockIdx.x * 64;
  __shared__ u16 tile[64][65];
  const int tid = threadIdx.x;
  const int tr = tid >> 3, ch = tid & 7;
#pragma unroll
  for (int i = 0; i < 2; ++i) {
    int t = tr + i * 32;
    s16x8 v = *(const s16x8*)&QKV[(b * 2048 + t0 + t) * 3072 + 2048 + h * 64 + ch * 8];
#pragma unroll
    for (int j = 0; j < 8; ++j) tile[t][ch * 8 + j] = (u16)v[j];
  }
  __syncthreads();
#pragma unroll
  for (int i = 0; i < 2; ++i) {
    int d = tr + i * 32;
    s16x8 o;
#pragma unroll
    for (int j = 0; j < 8; ++j) o[j] = (short)tile[ch * 8 + j][d];
    *(s16x8*)&Vtg[(bh * 64 + d) * 2048 + t0 + ch * 8] = o;
  }
}

// ---------- GEMM: C[M,N] = A[M,K] @ Bt[N,K]^T  (bf16 in, f32 acc) ----------
// 128xBN tile, BK=64, 4 waves. 2-phase pipeline: stage(t+1) before compute(t).
// BN=128: waves 2x2 (64x64 each). BN=64: waves 4x1 (32x64 each) -> 2x grid.
template <int F32OUT, int BN>
__global__ __launch_bounds__(256) void gemm_bt(const u16* __restrict__ A,
                                               const u16* __restrict__ Bt,
                                               u16* __restrict__ Cb,
                                               float* __restrict__ Cf,
                                               const float* __restrict__ bias,
                                               int M, int N, int K) {
  constexpr int WRN = (BN == 128) ? 2 : 4;  // waves along M
  constexpr int WRS = 128 / WRN;            // wave row stride (64 or 32)
  constexpr int MB = WRS / 16;              // row frags per wave (4 or 2)
  __shared__ alignas(16) u16 As[2][128 * 64];
  __shared__ alignas(16) u16 Bs[2][BN * 64];
  const int tid = threadIdx.x;
  const int lane = tid & 63, w = tid >> 6;
  const int wr = (BN == 128) ? (w >> 1) : w;
  const int wc = (BN == 128) ? (w & 1) : 0;
  const int g = lane >> 4, c15 = lane & 15;
  const int nbk = N / BN;
  const int bm = blockIdx.x / nbk, bn = blockIdx.x % nbk;

  f32x4 acc[MB][4] = {};

  const int srow = tid >> 3;        // 0..31 (+ i*32)
  const u16* Ag = A + (bm * 128 + srow) * K + (tid & 7) * 8;
  const u16* Bg = Bt + (bn * BN + srow) * K + (tid & 7) * 8;
  const int lds_e = tid * 8;        // + i*2048

  auto stage = [&](int kt, int buf) {
#pragma unroll
    for (int i = 0; i < 4; ++i) GLOAD_LDS16(Ag + i * 32 * K + kt, &As[buf][lds_e + i * 2048]);
#pragma unroll
    for (int i = 0; i < BN / 32; ++i) GLOAD_LDS16(Bg + i * 32 * K + kt, &Bs[buf][lds_e + i * 2048]);
  };

  stage(0, 0);
  __syncthreads();

  const int nkt = K >> 6;
  for (int t = 0; t < nkt; ++t) {
    const int c = t & 1;
    if (t + 1 < nkt) stage((t + 1) << 6, c ^ 1);
#pragma unroll
    for (int kc = 0; kc < 2; ++kc) {
      s16x8 a[MB], b[4];
#pragma unroll
      for (int mb = 0; mb < MB; ++mb)
        a[mb] = *(const s16x8*)&As[c][(wr * WRS + mb * 16 + c15) * 64 + kc * 32 + g * 8];
#pragma unroll
      for (int nb = 0; nb < 4; ++nb)
        b[nb] = *(const s16x8*)&Bs[c][(wc * 64 + nb * 16 + c15) * 64 + kc * 32 + g * 8];
#pragma unroll
      for (int mb = 0; mb < MB; ++mb)
#pragma unroll
        for (int nb = 0; nb < 4; ++nb) acc[mb][nb] = mfma16(a[mb], b[nb], acc[mb][nb]);
    }
    __syncthreads();  // publishes buf c^1 (vmcnt drained here, hidden by compute)
  }
#pragma unroll
  for (int mb = 0; mb < MB; ++mb) {
#pragma unroll
    for (int nb = 0; nb < 4; ++nb) {
      int row0 = bm * 128 + wr * WRS + mb * 16 + g * 4;
      int col = bn * BN + wc * 64 + nb * 16 + c15;
#pragma unroll
      for (int r = 0; r < 4; ++r) {
        float v = acc[mb][nb][r];
        if (F32OUT)
          Cf[(row0 + r) * N + col] = v + bias[col];
        else
          Cb[(row0 + r) * N + col] = f2bf(v);
      }
    }
  }
}

// ---------- flash attention ----------
// QKV [4096][3072] bf16 (row = b*2048+t, col = qkv*1024 + h*64 + d)
// Vtg [(b*16+h)*64+d][2048] bf16 (global V^T) — writer order b*16+h!
// AO: torch-raw-reshape layout: AO[(2h+b)*131072 + t*64 + d]  (as [4096][1024])
// Grid: 512 blocks x 512 threads (8 waves, 16 q-rows each -> 128 q-rows/block).
// XCD swizzle: wgid=(bid&7)*64+(bid>>3) -> 4 bh per XCD (K/V 2MB <= 4MB L2).
// Softmax kept in raw domain; scale folded into exp2 via fmaf; P/AO converted
// with native bf16 casts (v_cvt_pk_bf16_f32).
__global__ __launch_bounds__(512, 4) void attn_fwd(const u16* __restrict__ QKV,
                                                   const u16* __restrict__ Vtg,
                                                   u16* __restrict__ AO) {
  __shared__ alignas(16) u16 Ks[2][64 * 64];   // [key][d] swizzled
  __shared__ alignas(16) u16 Vt[2][64 * 64];   // [d][key] swizzled
  __shared__ alignas(16) u16 Ps[8][16 * 64];   // per-wave P [q][key] swizzled
  const int tid = threadIdx.x, lane = tid & 63, w = tid >> 6;
  const int bid = blockIdx.x;
  const int wgid = (bid & 7) * 64 + (bid >> 3);  // bijective XCD clustering
  const int qb = wgid & 15;        // 0..15 (128 q-rows each)
  const int bh = wgid >> 4;        // 0..31 (= 2h+b, AO order)
  const int h = bh >> 1, b = bh & 1;
  const int g = lane >> 4, c15 = lane & 15;
  const int bt0 = b * 2048;
  const float CS = 0.125f * LOG2E;  // scale folded with log2e

  // Q fragments (stay in regs): wave's rows = qb*128 + w*16 + c15
  s16x8 q[2];
#pragma unroll
  for (int kc = 0; kc < 2; ++kc) {
    int row = bt0 + qb * 128 + w * 16 + c15;
    q[kc] = *(const s16x8*)&QKV[row * 3072 + h * 64 + kc * 32 + g * 8];
  }

  f32x4 o[4] = {};
  float mrow = -1e30f, lrow = 0.f;  // per-lane: q-row = c15 (replicated over g)
                                    // mrow tracked in SCALED (log2) domain

  // staging indices (512 threads, one 16B chunk each per tile)
  const int srow = tid >> 3;        // 0..63 (key for K-stage, d for V-stage)
  const int sch = tid & 7;          // chunk 0..7
  const int ss7 = (srow & 7) ^ ((srow >> 3) & 7);
  const u16* Kg = QKV + (bt0 + srow) * 3072 + 1024 + h * 64 + ((sch ^ ss7) * 8);
  const u16* Vgt = Vtg + ((b * 16 + h) * 64 + srow) * 2048 + ((sch ^ ss7) * 8);

  auto stageKV = [&](int key0, int buf) {
    GLOAD_LDS16(Kg + key0 * 3072, &Ks[buf][tid * 8]);
    GLOAD_LDS16(Vgt + key0, &Vt[buf][tid * 8]);
  };

  stageKV(0, 0);
  __syncthreads();

  for (int t = 0; t < 32; ++t) {
    const int c = t & 1;
    if (t < 31) stageKV((t + 1) * 64, c ^ 1);

    // S^T = K Q^T: s[nb] lane holds S_raw[key=nb*16+g*4+r][q=c15]
    f32x4 s[4] = {};
    __builtin_amdgcn_s_setprio(1);
#pragma unroll
    for (int kc = 0; kc < 2; ++kc) {
      s16x8 kf[4];
#pragma unroll
      for (int nb = 0; nb < 4; ++nb) {
        int row = nb * 16 + c15;
        kf[nb] = *(const s16x8*)&Ks[c][row * 64 + ((kc * 32 + g * 8) ^ swzm(row))];
      }
#pragma unroll
      for (int nb = 0; nb < 4; ++nb) s[nb] = mfma16(kf[nb], q[kc], s[nb]);
    }
    __builtin_amdgcn_s_setprio(0);

    // softmax (raw-domain max; scale once; exp2 via fused fma)
    float m01 = fmaxf(fmaxf(s[0][0], s[0][1]), fmaxf(s[0][2], s[0][3]));
    float m11 = fmaxf(fmaxf(s[1][0], s[1][1]), fmaxf(s[1][2], s[1][3]));
    float m21 = fmaxf(fmaxf(s[2][0], s[2][1]), fmaxf(s[2][2], s[2][3]));
    float m31 = fmaxf(fmaxf(s[3][0], s[3][1]), fmaxf(s[3][2], s[3][3]));
    float mr = fmaxf(fmaxf(m01, m11), fmaxf(m21, m31));
    mr = fmaxf(mr, __shfl_xor(mr, 16, 64));
    mr = fmaxf(mr, __shfl_xor(mr, 32, 64));
    float m0s = mr * CS;  // scaled-domain tile max
    bool exceed = (m0s > mrow + 8.0f);
    if (__any(exceed)) {  // rescale (rare after warm-up)
      float mn = fmaxf(mrow, m0s);
      float alpha = exp2f(mrow - mn);
      mrow = mn;
      lrow *= alpha;
#pragma unroll
      for (int r = 0; r < 4; ++r) {
        float aB = __shfl(alpha, g * 4 + r, 64);  // c15-domain -> row-domain
#pragma unroll
        for (int db = 0; db < 4; ++db) o[db][r] *= aB;
      }
    }
    {
      float m = mrow;
#pragma unroll
      for (int nb = 0; nb < 4; ++nb)
#pragma unroll
        for (int r = 0; r < 4; ++r) s[nb][r] = exp2f(fmaf(s[nb][r], CS, -m));
      float s0 = (s[0][0] + s[0][1]) + (s[0][2] + s[0][3]);
      float s1 = (s[1][0] + s[1][1]) + (s[1][2] + s[1][3]);
      float s2 = (s[2][0] + s[2][1]) + (s[2][2] + s[2][3]);
      float s3 = (s[3][0] + s[3][1]) + (s[3][2] + s[3][3]);
      float rs = (s0 + s1) + (s2 + s3);
      rs += __shfl_xor(rs, 16, 64);
      rs += __shfl_xor(rs, 32, 64);
      lrow += rs;
      // P write: 4 consecutive keys (r=0..3) -> one b64 per nb (native cvt_pk)
      int row = c15;
#pragma unroll
      for (int nb = 0; nb < 4; ++nb) {
        bf16x4 pk = {(__bf16)s[nb][0], (__bf16)s[nb][1], (__bf16)s[nb][2],
                     (__bf16)s[nb][3]};
        *(bf16x4*)&Ps[w][row * 64 + ((nb * 16 + g * 4) ^ swzm(row))] = pk;
      }
    }

    // O += P @ V (o rows = q = g*4+r, cols = d = db*16+c15)
    __builtin_amdgcn_s_setprio(1);
#pragma unroll
    for (int kc = 0; kc < 2; ++kc) {
      s16x8 pf, vf[4];
      {
        int row = c15;
        pf = *(const s16x8*)&Ps[w][row * 64 + ((kc * 32 + g * 8) ^ swzm(row))];
      }
#pragma unroll
      for (int db = 0; db < 4; ++db) {
        int row = db * 16 + c15;
        vf[db] = *(const s16x8*)&Vt[c][row * 64 + ((kc * 32 + g * 8) ^ swzm(row))];
      }
#pragma unroll
      for (int db = 0; db < 4; ++db) o[db] = mfma16(pf, vf[db], o[db]);
    }
    __builtin_amdgcn_s_setprio(0);

    __syncthreads();  // publishes buf c^1 (vmcnt drain hidden by compute)
  }

  // epilogue: O / l (broadcast lrow c15-domain -> row-domain), torch-raw layout
#pragma unroll
  for (int r = 0; r < 4; ++r) {
    float lB = __shfl(lrow, g * 4 + r, 64);
    float rinv = 1.0f / lB;
    int trow = qb * 128 + w * 16 + g * 4 + r;
#pragma unroll
    for (int db = 0; db < 4; ++db)
      AO[(2 * h + b) * 131072 + trow * 64 + db * 16 + c15] =
          __builtin_bit_cast(u16, (__bf16)(o[db][r] * rinv));
  }
}

// ---------- launch ----------
extern "C" void kernel_launch(void* const* d_in, const int* in_sizes, int n_in,
                              void* d_out, int out_size, void* d_ws, size_t ws_size,
                              hipStream_t stream) {
  const float* x = (const float*)d_in[0];
  const float* Wq = (const float*)d_in[1];
  const float* Wk = (const float*)d_in[2];
  const float* Wv = (const float*)d_in[3];
  const float* Wp = (const float*)d_in[4];
  const float* bp = (const float*)d_in[5];
  float* out = (float*)d_out;

  u16* Xb = (u16*)d_ws;                   // [4096][1024]  (reused as Vtg later)
  u16* Wt = Xb + 4096 * 1024;             // [3072][1024]
  u16* WpT = Wt + 3072 * 1024;            // [1024][1024]
  u16* QKV = WpT + 1024 * 1024;           // [4096][3072]
  u16* AO = QKV + 4096 * 3072;            // [4096][1024]
  u16* Vtg = Xb;                          // [32*64][2048] — Xb dead after gemm1

  k_cast_bf16<<<4096, 256, 0, stream>>>(x, Xb);
  k_wqkv<<<dim3(16, 48), 256, 0, stream>>>(Wq, Wk, Wv, Wt);
  k_wp<<<dim3(16, 16), 256, 0, stream>>>(Wp, WpT);
  gemm_bt<0, 128><<<dim3(32 * 24), 256, 0, stream>>>(Xb, Wt, QKV, nullptr, nullptr, 4096, 3072, 1024);
  k_vt<<<dim3(32, 32), 256, 0, stream>>>(QKV, Vtg);
  attn_fwd<<<512, 512, 0, stream>>>(QKV, Vtg, AO);
  gemm_bt<1, 64><<<dim3(32 * 16), 256, 0, stream>>>(AO, WpT, nullptr, out, bp, 4096, 1024, 1024);
}